// Round 1
// baseline (166.426 us; speedup 1.0000x reference)
//
#include <hip/hip_runtime.h>
#include <stdint.h>

#define BB 256
#define DD 128
#define KK 32
#define MM1 64
#define MM2 32

typedef __attribute__((ext_vector_type(8))) short bf16x8;
typedef __attribute__((ext_vector_type(4))) float f32x4;

__device__ __forceinline__ short f2b(float f) {
  uint32_t u = __builtin_bit_cast(uint32_t, f);
  u += 0x7FFFu + ((u >> 16) & 1u);          // RNE to bf16
  return (short)(u >> 16);
}
__device__ __forceinline__ float sigmoidf_fast(float xv) {
  return __builtin_amdgcn_rcpf(1.0f + __expf(-xv));
}

// ---------------------------------------------------------------------------
// Kernel A: VAE on beta_w -> mu, logvar (to d_out), recon (to ws)
// ---------------------------------------------------------------------------
__global__ __launch_bounds__(128) void vae_kernel(
    const float* __restrict__ betaw,
    const float* __restrict__ enc1w, const float* __restrict__ enc1b,
    const float* __restrict__ enc2w, const float* __restrict__ enc2b,
    const float* __restrict__ muw,  const float* __restrict__ mub,
    const float* __restrict__ lvw,  const float* __restrict__ lvb,
    const float* __restrict__ dec1w, const float* __restrict__ dec1b,
    const float* __restrict__ dec2w, const float* __restrict__ dec2b,
    const float* __restrict__ dec3w, const float* __restrict__ dec3b,
    const float* __restrict__ eps,
    float* __restrict__ mu_out, float* __restrict__ lv_out,
    float* __restrict__ recon_out)
{
  const int b = blockIdx.x, t = threadIdx.x;
  __shared__ float bw[KK], e1[128], e2[64], zz[32], d1s[64];
  if (t < KK) bw[t] = betaw[b * KK + t];
  __syncthreads();
  // enc1: K->128
  {
    float acc = enc1b[t];
    #pragma unroll
    for (int k = 0; k < KK; ++k) acc = fmaf(bw[k], enc1w[k * 128 + t], acc);
    e1[t] = fmaxf(acc, 0.f);
  }
  __syncthreads();
  if (t < 64) {                        // enc2: 128->64
    float a2 = enc2b[t];
    #pragma unroll 8
    for (int h = 0; h < 128; ++h) a2 = fmaf(e1[h], enc2w[h * 64 + t], a2);
    e2[t] = fmaxf(a2, 0.f);
  }
  __syncthreads();
  if (t < 32) {                        // mu / logvar / z
    float m = mub[t], l = lvb[t];
    #pragma unroll 8
    for (int h = 0; h < 64; ++h) {
      float e = e2[h];
      m = fmaf(e, muw[h * 32 + t], m);
      l = fmaf(e, lvw[h * 32 + t], l);
    }
    mu_out[b * 32 + t] = m;
    lv_out[b * 32 + t] = l;
    zz[t] = fmaf(eps[b * 32 + t], __expf(0.5f * l), m);
  }
  __syncthreads();
  if (t < 64) {                        // dec1: 32->64
    float a3 = dec1b[t];
    #pragma unroll
    for (int l = 0; l < 32; ++l) a3 = fmaf(zz[l], dec1w[l * 64 + t], a3);
    d1s[t] = fmaxf(a3, 0.f);
  }
  __syncthreads();
  float d2v;                           // dec2: 64->128 (all 128 threads)
  {
    float a4 = dec2b[t];
    #pragma unroll 8
    for (int h = 0; h < 64; ++h) a4 = fmaf(d1s[h], dec2w[h * 128 + t], a4);
    d2v = fmaxf(a4, 0.f);
  }
  __syncthreads();
  __shared__ float d2s[128];
  d2s[t] = d2v;
  __syncthreads();
  if (t < 32) {                        // dec3: 128->K
    float a5 = dec3b[t];
    #pragma unroll 8
    for (int h = 0; h < 128; ++h) a5 = fmaf(d2s[h], dec3w[h * 32 + t], a5);
    recon_out[b * 32 + t] = a5;
  }
}

// ---------------------------------------------------------------------------
// Kernel B: per (d, b-half) fused phi -> sigmoid -> LC stack -> y1/y2
// ---------------------------------------------------------------------------
__global__ __launch_bounds__(512) void main_kernel(
    const float* __restrict__ x,
    const float* __restrict__ W1p, const float* __restrict__ W1n,
    const float* __restrict__ b1p, const float* __restrict__ b1n,
    const float* __restrict__ lc1w, const float* __restrict__ lc1b,
    const float* __restrict__ lc2w, const float* __restrict__ lc2b,
    const float* __restrict__ betaw, const float* __restrict__ betab,
    const float* __restrict__ recon,
    float* __restrict__ out)
{
  const int bx = blockIdx.x;
  const int d = bx >> 1;
  const int b0 = (bx & 1) * 128;
  const int tid = threadIdx.x;
  const int wave = tid >> 6;
  const int lane = tid & 63;

  __shared__ __align__(16) short sS[128 * 64];      // bf16 s[bb][m], swizzled
  __shared__ __align__(16) float betaS[128 * 32];
  __shared__ __align__(16) float reconS[128 * 32];
  __shared__ __align__(16) float lc2S[KK * MM2];
  __shared__ __align__(16) float lc1bS[KK * MM2];
  __shared__ float lc2bS[KK];
  __shared__ float b1S[MM1];
  // union region: phase1 = xs[128][128] bf16 (0..16384) + w1s[64][128] bf16
  // (16384..24576); phase2 = lcs_half[512 c'][64 m] bf16 (0..32768)
  __shared__ __align__(16) short uni[32768];

  // ---------------- stage phase-1 operands ----------------
  {
    const float4* xsrc = (const float4*)(x + b0 * DD);
    for (int e = tid; e < 4096; e += 512) {
      float4 v = xsrc[e];
      int row = e >> 5;
      int i = (e & 31) * 4;
      int ib = i & ~7, il = i & 7;
      short4 o; o.x = f2b(v.x); o.y = f2b(v.y); o.z = f2b(v.z); o.w = f2b(v.w);
      *(short4*)&uni[row * 128 + (ib ^ ((row & 7) << 3)) + il] = o;
    }
    const float4* wp = (const float4*)(W1p + d * MM1 * DD);
    const float4* wn = (const float4*)(W1n + d * MM1 * DD);
    for (int e = tid; e < 2048; e += 512) {
      float4 p = wp[e], n = wn[e];
      int m = e >> 5;
      int i = (e & 31) * 4;
      int ib = i & ~7, il = i & 7;
      short4 o; o.x = f2b(p.x - n.x); o.y = f2b(p.y - n.y);
      o.z = f2b(p.z - n.z); o.w = f2b(p.w - n.w);
      *(short4*)&uni[16384 + m * 128 + (ib ^ ((m & 7) << 3)) + il] = o;
    }
    if (tid < MM1) b1S[tid] = b1p[d * MM1 + tid] - b1n[d * MM1 + tid];
    const float4* bws = (const float4*)(betaw + b0 * KK);
    const float4* rcs = (const float4*)(recon + b0 * KK);
    for (int e = tid; e < 1024; e += 512) {
      ((float4*)betaS)[e]  = bws[e];
      ((float4*)reconS)[e] = rcs[e];
    }
    if (tid < 256) {
      ((float4*)lc2S)[tid]  = ((const float4*)lc2w)[tid];
      ((float4*)lc1bS)[tid] = ((const float4*)lc1b)[tid];
    }
    if (tid < KK) lc2bS[tid] = lc2b[tid];
  }
  __syncthreads();

  // ---------------- phase 1: phi = x @ W1d^T + b1; s = sigmoid(phi) ----------
  {
    const int row = wave * 16 + (lane & 15);
    const int kof = (lane >> 4) * 8;
    const int rsw = (row & 7) << 3;
    bf16x8 a[4];
    #pragma unroll
    for (int ks = 0; ks < 4; ++ks)
      a[ks] = *(const bf16x8*)&uni[row * 128 + ((ks * 32 + kof) ^ rsw)];
    #pragma unroll
    for (int ct = 0; ct < 4; ++ct) {
      const int m = ct * 16 + (lane & 15);
      const int msw = (m & 7) << 3;
      f32x4 acc = {0.f, 0.f, 0.f, 0.f};
      #pragma unroll
      for (int ks = 0; ks < 4; ++ks) {
        bf16x8 bf = *(const bf16x8*)&uni[16384 + m * 128 + ((ks * 32 + kof) ^ msw)];
        acc = __builtin_amdgcn_mfma_f32_16x16x32_bf16(a[ks], bf, acc, 0, 0, 0);
      }
      const float bias = b1S[m];
      #pragma unroll
      for (int r = 0; r < 4; ++r) {
        int bb = wave * 16 + (lane >> 4) * 4 + r;
        float s = sigmoidf_fast(acc[r] + bias);
        int mhi = m & ~7, mlo = m & 7;
        sS[bb * 64 + (mhi ^ ((bb & 7) << 3)) + mlo] = f2b(s);
      }
    }
  }
  __syncthreads();

  // ---------------- phase 2: h1 = s @ lc1 (fused sigmoid/lc2/y-dots) --------
  float y1a[4] = {0, 0, 0, 0}, y2a[4] = {0, 0, 0, 0};
  bf16x8 sa[2];
  {
    const int row = wave * 16 + (lane & 15);
    const int kofl = (lane >> 4) * 8;
    const int rsw = (row & 7) << 3;
    sa[0] = *(const bf16x8*)&sS[row * 64 + ((0 + kofl) ^ rsw)];
    sa[1] = *(const bf16x8*)&sS[row * 64 + ((32 + kofl) ^ rsw)];
  }
  const int n0 = lane & 15;
  const int kof = (lane >> 4) * 8;
  #pragma unroll 1
  for (int kh = 0; kh < 2; ++kh) {
    __syncthreads();                    // everyone done with uni before restage
    {
      const float* src = lc1w + kh * 32768;
      for (int e = tid; e < 32768; e += 512) {
        int kq = e >> 11;
        int m = (e >> 5) & 63;
        int n = e & 31;
        int cp = kq * 32 + n;           // c' = local-k*32 + n
        uni[cp * 64 + ((m & ~7) ^ ((cp & 7) << 3)) + (m & 7)] = f2b(src[e]);
      }
    }
    __syncthreads();
    for (int kk = 0; kk < 16; ++kk) {
      const int k = kh * 16 + kk;
      const int c0 = kk * 32 + n0, c1 = c0 + 16;
      const float bi0 = lc1bS[k * 32 + n0], bi1 = lc1bS[k * 32 + n0 + 16];
      f32x4 acc0 = {bi0, bi0, bi0, bi0}, acc1 = {bi1, bi1, bi1, bi1};
      #pragma unroll
      for (int mh = 0; mh < 2; ++mh) {
        int mb = mh * 32 + kof;
        bf16x8 bf0 = *(const bf16x8*)&uni[c0 * 64 + (mb ^ ((c0 & 7) << 3))];
        bf16x8 bf1 = *(const bf16x8*)&uni[c1 * 64 + (mb ^ ((c1 & 7) << 3))];
        acc0 = __builtin_amdgcn_mfma_f32_16x16x32_bf16(sa[mh], bf0, acc0, 0, 0, 0);
        acc1 = __builtin_amdgcn_mfma_f32_16x16x32_bf16(sa[mh], bf1, acc1, 0, 0, 0);
      }
      const float w0 = lc2S[k * 32 + n0], w1 = lc2S[k * 32 + n0 + 16];
      float v[4];
      #pragma unroll
      for (int r = 0; r < 4; ++r)
        v[r] = fmaf(sigmoidf_fast(acc0[r]), w0, sigmoidf_fast(acc1[r]) * w1);
      #pragma unroll
      for (int msk = 1; msk <= 8; msk <<= 1) {
        #pragma unroll
        for (int r = 0; r < 4; ++r) v[r] += __shfl_xor(v[r], msk, 64);
      }
      const float l2b = lc2bS[k];
      #pragma unroll
      for (int r = 0; r < 4; ++r) {
        int bb = wave * 16 + (lane >> 4) * 4 + r;
        float h2 = v[r] + l2b;
        y1a[r] = fmaf(h2, betaS[bb * 32 + k], y1a[r]);
        y2a[r] = fmaf(h2, reconS[bb * 32 + k], y2a[r]);
      }
    }
  }

  if ((lane & 15) == 0) {
    #pragma unroll
    for (int r = 0; r < 4; ++r) {
      int row = b0 + wave * 16 + (lane >> 4) * 4 + r;
      float bconst = betab[row];
      out[row * DD + d] = y1a[r] + bconst;                 // y1
      out[BB * DD + row * DD + d] = y2a[r] + bconst;       // y2
    }
  }
}

// ---------------------------------------------------------------------------
extern "C" void kernel_launch(void* const* d_in, const int* in_sizes, int n_in,
                              void* d_out, int out_size, void* d_ws, size_t ws_size,
                              hipStream_t stream) {
  const float* x     = (const float*)d_in[0];
  const float* W1p   = (const float*)d_in[1];
  const float* W1n   = (const float*)d_in[2];
  const float* b1p   = (const float*)d_in[3];
  const float* b1n   = (const float*)d_in[4];
  const float* lc1w  = (const float*)d_in[5];
  const float* lc1b  = (const float*)d_in[6];
  const float* lc2w  = (const float*)d_in[7];
  const float* lc2b  = (const float*)d_in[8];
  const float* betaw = (const float*)d_in[9];
  const float* betab = (const float*)d_in[10];
  const float* enc1w = (const float*)d_in[11];
  const float* enc1b = (const float*)d_in[12];
  const float* enc2w = (const float*)d_in[13];
  const float* enc2b = (const float*)d_in[14];
  const float* muw   = (const float*)d_in[15];
  const float* mub   = (const float*)d_in[16];
  const float* lvw   = (const float*)d_in[17];
  const float* lvb   = (const float*)d_in[18];
  const float* dec1w = (const float*)d_in[19];
  const float* dec1b = (const float*)d_in[20];
  const float* dec2w = (const float*)d_in[21];
  const float* dec2b = (const float*)d_in[22];
  const float* dec3w = (const float*)d_in[23];
  const float* dec3b = (const float*)d_in[24];
  const float* eps   = (const float*)d_in[25];

  float* out   = (float*)d_out;
  float* recon = (float*)d_ws;                 // [B, K] scratch

  float* mu_out = out + BB * DD * 2;           // 65536
  float* lv_out = mu_out + BB * 32;            // 73728

  vae_kernel<<<dim3(BB), dim3(128), 0, stream>>>(
      betaw, enc1w, enc1b, enc2w, enc2b, muw, mub, lvw, lvb,
      dec1w, dec1b, dec2w, dec2b, dec3w, dec3b, eps,
      mu_out, lv_out, recon);

  main_kernel<<<dim3(256), dim3(512), 0, stream>>>(
      x, W1p, W1n, b1p, b1n, lc1w, lc1b, lc2w, lc2b,
      betaw, betab, recon, out);
}

// Round 2
// 148.902 us; speedup vs baseline: 1.1177x; 1.1177x over previous
//
#include <hip/hip_runtime.h>
#include <stdint.h>

#define BB 256
#define DD 128
#define KK 32
#define MM1 64
#define MM2 32

typedef __attribute__((ext_vector_type(8))) short bf16x8;
typedef __attribute__((ext_vector_type(4))) float f32x4;

#define LOG2E 1.44269504088896f

// ---- ws layout (bytes) ----
// 0       reconT  f32 [32][256]   (vae)        32KB
// 32768   betaT   f32 [32][256]   (prep)       32KB
// 65536   xbf     bf16[256][128]  (prep)       64KB
// 131072  lc1T    bf16[1024][64]  (prep) rows cp=k*32+n, cols m   128KB
// 262144  lc1bs   f32 [32][32]  = -lc1b*LOG2E  4KB
// 266240  lc2bq   f32 [32]      = 0.25*lc2b
// 270336  b1s     f32 [128][64] = -(b1p-b1n)*LOG2E   32KB
// 303104  w1bf    bf16[128][64][128]           2MB

__device__ __forceinline__ short f2b(float f) {
  uint32_t u = __builtin_bit_cast(uint32_t, f);
  u += 0x7FFFu + ((u >> 16) & 1u);          // RNE to bf16
  return (short)(u >> 16);
}
__device__ __forceinline__ float sigm_pre(float acc, float cpre) {
  // sigmoid(acc + bias) with cpre = -bias*LOG2E
  return __builtin_amdgcn_rcpf(
      1.0f + __builtin_amdgcn_exp2f(fmaf(acc, -LOG2E, cpre)));
}

// ---------------------------------------------------------------------------
// Prep: all dtype conversion / transposition, once.
// grid 1024 x 256  (tid covers 262144 = W1 float4 count exactly)
// ---------------------------------------------------------------------------
__global__ __launch_bounds__(256) void prep_kernel(
    const float* __restrict__ x, const float* __restrict__ W1p,
    const float* __restrict__ W1n, const float* __restrict__ b1p,
    const float* __restrict__ b1n, const float* __restrict__ lc1w,
    const float* __restrict__ lc1b, const float* __restrict__ lc2b,
    const float* __restrict__ betaw, char* __restrict__ ws)
{
  const int tid = blockIdx.x * 256 + threadIdx.x;   // 0..262143

  { // W1bf = bf16(W1p - W1n), linear [d][m][i], 262144 float4
    float4 a = ((const float4*)W1p)[tid];
    float4 b = ((const float4*)W1n)[tid];
    short4 s;
    s.x = f2b(a.x - b.x); s.y = f2b(a.y - b.y);
    s.z = f2b(a.z - b.z); s.w = f2b(a.w - b.w);
    ((short4*)(ws + 303104))[tid] = s;
  }
  if (tid < 8192) { // xbf, 32768 elems = 8192 float4
    float4 v = ((const float4*)x)[tid];
    short4 s;
    s.x = f2b(v.x); s.y = f2b(v.y); s.z = f2b(v.z); s.w = f2b(v.w);
    ((short4*)(ws + 65536))[tid] = s;
  }
  if (tid < 65536) { // lc1T[(k*32+n)*64 + m] = lc1w[k][m][n]
    int k = tid >> 11, n = (tid >> 6) & 31, m = tid & 63;
    ((short*)(ws + 131072))[tid] = f2b(lc1w[k * 2048 + m * 32 + n]);
  }
  if (tid < 8192) { // betaT[k*256 + b]
    ((float*)(ws + 32768))[tid] = betaw[(tid & 255) * 32 + (tid >> 8)];
  }
  if (tid < 1024) { // lc1bs = -lc1b * LOG2E
    ((float*)(ws + 262144))[tid] = -lc1b[tid] * LOG2E;
  }
  if (tid < 32) { ((float*)(ws + 266240))[tid] = 0.25f * lc2b[tid]; }
  if (tid < 8192) { // b1s = -(b1p-b1n)*LOG2E
    ((float*)(ws + 270336))[tid] = -(b1p[tid] - b1n[tid]) * LOG2E;
  }
}

// ---------------------------------------------------------------------------
// VAE on beta_w -> mu, logvar (d_out), reconT (ws, transposed [k][b])
// ---------------------------------------------------------------------------
__global__ __launch_bounds__(128) void vae_kernel(
    const float* __restrict__ betaw,
    const float* __restrict__ enc1w, const float* __restrict__ enc1b,
    const float* __restrict__ enc2w, const float* __restrict__ enc2b,
    const float* __restrict__ muw,  const float* __restrict__ mub,
    const float* __restrict__ lvw,  const float* __restrict__ lvb,
    const float* __restrict__ dec1w, const float* __restrict__ dec1b,
    const float* __restrict__ dec2w, const float* __restrict__ dec2b,
    const float* __restrict__ dec3w, const float* __restrict__ dec3b,
    const float* __restrict__ eps,
    float* __restrict__ mu_out, float* __restrict__ lv_out,
    float* __restrict__ reconT)
{
  const int b = blockIdx.x, t = threadIdx.x;
  __shared__ float bw[KK], e1[128], e2[64], zz[32], d1s[64], d2s[128];
  if (t < KK) bw[t] = betaw[b * KK + t];
  __syncthreads();
  { // enc1: K->128
    float a0 = enc1b[t], a1 = 0.f;
    #pragma unroll
    for (int k = 0; k < KK; k += 2) {
      a0 = fmaf(bw[k], enc1w[k * 128 + t], a0);
      a1 = fmaf(bw[k + 1], enc1w[(k + 1) * 128 + t], a1);
    }
    e1[t] = fmaxf(a0 + a1, 0.f);
  }
  __syncthreads();
  if (t < 64) { // enc2: 128->64
    float a0 = enc2b[t], a1 = 0.f, a2 = 0.f, a3 = 0.f;
    #pragma unroll 8
    for (int h = 0; h < 128; h += 4) {
      a0 = fmaf(e1[h], enc2w[h * 64 + t], a0);
      a1 = fmaf(e1[h + 1], enc2w[(h + 1) * 64 + t], a1);
      a2 = fmaf(e1[h + 2], enc2w[(h + 2) * 64 + t], a2);
      a3 = fmaf(e1[h + 3], enc2w[(h + 3) * 64 + t], a3);
    }
    e2[t] = fmaxf((a0 + a1) + (a2 + a3), 0.f);
  }
  __syncthreads();
  if (t < 32) { // mu / logvar / z
    float m0 = mub[t], m1 = 0.f, l0 = lvb[t], l1 = 0.f;
    #pragma unroll 8
    for (int h = 0; h < 64; h += 2) {
      float ea = e2[h], eb = e2[h + 1];
      m0 = fmaf(ea, muw[h * 32 + t], m0);
      m1 = fmaf(eb, muw[(h + 1) * 32 + t], m1);
      l0 = fmaf(ea, lvw[h * 32 + t], l0);
      l1 = fmaf(eb, lvw[(h + 1) * 32 + t], l1);
    }
    float m = m0 + m1, l = l0 + l1;
    mu_out[b * 32 + t] = m;
    lv_out[b * 32 + t] = l;
    zz[t] = fmaf(eps[b * 32 + t], __expf(0.5f * l), m);
  }
  __syncthreads();
  if (t < 64) { // dec1: 32->64
    float a0 = dec1b[t], a1 = 0.f;
    #pragma unroll
    for (int l = 0; l < 32; l += 2) {
      a0 = fmaf(zz[l], dec1w[l * 64 + t], a0);
      a1 = fmaf(zz[l + 1], dec1w[(l + 1) * 64 + t], a1);
    }
    d1s[t] = fmaxf(a0 + a1, 0.f);
  }
  __syncthreads();
  { // dec2: 64->128
    float a0 = dec2b[t], a1 = 0.f, a2 = 0.f, a3 = 0.f;
    #pragma unroll 8
    for (int h = 0; h < 64; h += 4) {
      a0 = fmaf(d1s[h], dec2w[h * 128 + t], a0);
      a1 = fmaf(d1s[h + 1], dec2w[(h + 1) * 128 + t], a1);
      a2 = fmaf(d1s[h + 2], dec2w[(h + 2) * 128 + t], a2);
      a3 = fmaf(d1s[h + 3], dec2w[(h + 3) * 128 + t], a3);
    }
    d2s[t] = fmaxf((a0 + a1) + (a2 + a3), 0.f);
  }
  __syncthreads();
  if (t < 32) { // dec3: 128->K, transposed write
    float a0 = dec3b[t], a1 = 0.f, a2 = 0.f, a3 = 0.f;
    #pragma unroll 8
    for (int h = 0; h < 128; h += 4) {
      a0 = fmaf(d2s[h], dec3w[h * 32 + t], a0);
      a1 = fmaf(d2s[h + 1], dec3w[(h + 1) * 32 + t], a1);
      a2 = fmaf(d2s[h + 2], dec3w[(h + 2) * 32 + t], a2);
      a3 = fmaf(d2s[h + 3], dec3w[(h + 3) * 32 + t], a3);
    }
    reconT[t * BB + b] = (a0 + a1) + (a2 + a3);
  }
}

// ---------------------------------------------------------------------------
// Main: 1024 blocks x 256 thr. block = (d = bx>>3, bg = bx&7 -> 32 b rows).
// 4 waves: phase1 split by m-tile; phase2 split by k (8 k each).
// ---------------------------------------------------------------------------
__global__ __launch_bounds__(256) void main_kernel(
    const float* __restrict__ lc2w, const float* __restrict__ betab,
    const char* __restrict__ ws, float* __restrict__ out)
{
  const int bx = blockIdx.x;
  const int d = bx >> 3;
  const int bg = bx & 7;
  const int tid = threadIdx.x;
  const int wave = tid >> 6, lane = tid & 63;
  const int g = lane >> 4, l15 = lane & 15;
  const int gb0 = bg * 32 + l15, gb1 = gb0 + 16;

  const short* __restrict__ xbf   = (const short*)(ws + 65536);
  const short* __restrict__ lc1T  = (const short*)(ws + 131072);
  const float* __restrict__ lc1bs = (const float*)(ws + 262144);
  const float* __restrict__ lc2bq = (const float*)(ws + 266240);
  const float* __restrict__ b1s   = (const float*)(ws + 270336) + d * MM1;
  const short* __restrict__ w1bf  = (const short*)(ws + 303104) + d * (MM1 * DD);
  const float* __restrict__ betaT = (const float*)(ws + 32768);
  const float* __restrict__ recT  = (const float*)(ws + 0);

  __shared__ short sS[32 * 64];       // sigma(phi), swizzled, 4KB
  __shared__ float yred[4][64];

  // ---------------- phase 1: this wave computes m-tile ct = wave -----------
  {
    bf16x8 wbv[4];
    const int m = wave * 16 + l15;
    #pragma unroll
    for (int ks = 0; ks < 4; ++ks)
      wbv[ks] = *(const bf16x8*)(w1bf + m * DD + ks * 32 + g * 8);
    const float cpre = b1s[m];        // already -bias*LOG2E
    #pragma unroll
    for (int rt = 0; rt < 2; ++rt) {
      f32x4 acc = {0.f, 0.f, 0.f, 0.f};
      #pragma unroll
      for (int ks = 0; ks < 4; ++ks) {
        bf16x8 xa = *(const bf16x8*)(xbf + (bg * 32 + rt * 16 + l15) * DD +
                                     ks * 32 + g * 8);
        acc = __builtin_amdgcn_mfma_f32_16x16x32_bf16(xa, wbv[ks], acc, 0, 0, 0);
      }
      #pragma unroll
      for (int r = 0; r < 4; ++r) {
        const int bl = rt * 16 + g * 4 + r;
        float s = sigm_pre(acc[r], cpre);
        sS[bl * 64 + ((m & ~7) ^ ((bl & 7) << 3)) + (m & 7)] = f2b(s);
      }
    }
  }
  __syncthreads();

  // ---------------- phase 2: B-frags (loop-invariant) ----------------------
  const bf16x8 sa0 = *(const bf16x8*)&sS[l15 * 64 + ((g * 8) ^ ((l15 & 7) << 3))];
  const bf16x8 sa1 = *(const bf16x8*)&sS[l15 * 64 + ((32 + g * 8) ^ ((l15 & 7) << 3))];
  const bf16x8 sa2 = *(const bf16x8*)&sS[(16 + l15) * 64 + ((g * 8) ^ ((l15 & 7) << 3))];
  const bf16x8 sa3 = *(const bf16x8*)&sS[(16 + l15) * 64 + ((32 + g * 8) ^ ((l15 & 7) << 3))];

  float y1a = 0.f, y2a = 0.f, y1b = 0.f, y2b = 0.f;
  bf16x8 A0a, A1a, A2a, A3a, A0b, A1b, A2b, A3b;

#define PREFA(kk, S) { \
    const short* ap = lc1T + (kk) * 2048 + l15 * 64 + g * 8; \
    A0##S = *(const bf16x8*)(ap); \
    A1##S = *(const bf16x8*)(ap + 32); \
    A2##S = *(const bf16x8*)(ap + 1024); \
    A3##S = *(const bf16x8*)(ap + 1056); }

#define COMPUTE(kk, S) { \
    f32x4 acc00 = {0,0,0,0}, acc01 = {0,0,0,0}; \
    f32x4 acc10 = {0,0,0,0}, acc11 = {0,0,0,0}; \
    acc00 = __builtin_amdgcn_mfma_f32_16x16x32_bf16(A0##S, sa0, acc00, 0, 0, 0); \
    acc00 = __builtin_amdgcn_mfma_f32_16x16x32_bf16(A1##S, sa1, acc00, 0, 0, 0); \
    acc01 = __builtin_amdgcn_mfma_f32_16x16x32_bf16(A0##S, sa2, acc01, 0, 0, 0); \
    acc01 = __builtin_amdgcn_mfma_f32_16x16x32_bf16(A1##S, sa3, acc01, 0, 0, 0); \
    acc10 = __builtin_amdgcn_mfma_f32_16x16x32_bf16(A2##S, sa0, acc10, 0, 0, 0); \
    acc10 = __builtin_amdgcn_mfma_f32_16x16x32_bf16(A3##S, sa1, acc10, 0, 0, 0); \
    acc11 = __builtin_amdgcn_mfma_f32_16x16x32_bf16(A2##S, sa2, acc11, 0, 0, 0); \
    acc11 = __builtin_amdgcn_mfma_f32_16x16x32_bf16(A3##S, sa3, acc11, 0, 0, 0); \
    f32x4 w0 = *(const f32x4*)(lc2w + (kk) * 32 + g * 4); \
    f32x4 w1 = *(const f32x4*)(lc2w + (kk) * 32 + 16 + g * 4); \
    f32x4 c0 = *(const f32x4*)(lc1bs + (kk) * 32 + g * 4); \
    f32x4 c1 = *(const f32x4*)(lc1bs + (kk) * 32 + 16 + g * 4); \
    float va = lc2bq[kk], vb = va; \
    _Pragma("unroll") \
    for (int r = 0; r < 4; ++r) { \
      va = fmaf(sigm_pre(acc00[r], c0[r]), w0[r], va); \
      va = fmaf(sigm_pre(acc10[r], c1[r]), w1[r], va); \
      vb = fmaf(sigm_pre(acc01[r], c0[r]), w0[r], vb); \
      vb = fmaf(sigm_pre(acc11[r], c1[r]), w1[r], vb); \
    } \
    y1a = fmaf(va, betaT[(kk) * BB + gb0], y1a); \
    y2a = fmaf(va, recT[(kk) * BB + gb0], y2a); \
    y1b = fmaf(vb, betaT[(kk) * BB + gb1], y1b); \
    y2b = fmaf(vb, recT[(kk) * BB + gb1], y2b); }

  const int k0 = wave * 8;
  PREFA(k0, a);
  #pragma unroll
  for (int kk = 0; kk < 8; kk += 2) {
    PREFA(k0 + kk + 1, b);
    COMPUTE(k0 + kk, a);
    if (kk < 6) PREFA(k0 + kk + 2, a);
    COMPUTE(k0 + kk + 1, b);
  }
#undef PREFA
#undef COMPUTE

  // ---------------- reduce across g-groups, then across waves --------------
  y1a += __shfl_xor(y1a, 16, 64); y1a += __shfl_xor(y1a, 32, 64);
  y2a += __shfl_xor(y2a, 16, 64); y2a += __shfl_xor(y2a, 32, 64);
  y1b += __shfl_xor(y1b, 16, 64); y1b += __shfl_xor(y1b, 32, 64);
  y2b += __shfl_xor(y2b, 16, 64); y2b += __shfl_xor(y2b, 32, 64);

  if (g == 0) {
    yred[wave][l15 * 2 + 0] = y1a;
    yred[wave][l15 * 2 + 1] = y2a;
    yred[wave][32 + l15 * 2 + 0] = y1b;
    yred[wave][32 + l15 * 2 + 1] = y2b;
  }
  __syncthreads();
  if (tid < 64) {
    float s = yred[0][tid] + yred[1][tid] + yred[2][tid] + yred[3][tid];
    const int rt = tid >> 5, q = tid & 31, l = q >> 1, o = q & 1;
    const int b = bg * 32 + rt * 16 + l;
    s += betab[b];
    out[o * (BB * DD) + b * DD + d] = s;
  }
}

// ---------------------------------------------------------------------------
extern "C" void kernel_launch(void* const* d_in, const int* in_sizes, int n_in,
                              void* d_out, int out_size, void* d_ws, size_t ws_size,
                              hipStream_t stream) {
  const float* x     = (const float*)d_in[0];
  const float* W1p   = (const float*)d_in[1];
  const float* W1n   = (const float*)d_in[2];
  const float* b1p   = (const float*)d_in[3];
  const float* b1n   = (const float*)d_in[4];
  const float* lc1w  = (const float*)d_in[5];
  const float* lc1b  = (const float*)d_in[6];
  const float* lc2w  = (const float*)d_in[7];
  const float* lc2b  = (const float*)d_in[8];
  const float* betaw = (const float*)d_in[9];
  const float* betab = (const float*)d_in[10];
  const float* enc1w = (const float*)d_in[11];
  const float* enc1b = (const float*)d_in[12];
  const float* enc2w = (const float*)d_in[13];
  const float* enc2b = (const float*)d_in[14];
  const float* muw   = (const float*)d_in[15];
  const float* mub   = (const float*)d_in[16];
  const float* lvw   = (const float*)d_in[17];
  const float* lvb   = (const float*)d_in[18];
  const float* dec1w = (const float*)d_in[19];
  const float* dec1b = (const float*)d_in[20];
  const float* dec2w = (const float*)d_in[21];
  const float* dec2b = (const float*)d_in[22];
  const float* dec3w = (const float*)d_in[23];
  const float* dec3b = (const float*)d_in[24];
  const float* eps   = (const float*)d_in[25];

  float* out    = (float*)d_out;
  char*  ws     = (char*)d_ws;
  float* reconT = (float*)ws;                   // [32][256]
  float* mu_out = out + BB * DD * 2;            // 65536
  float* lv_out = mu_out + BB * 32;             // 73728

  prep_kernel<<<dim3(1024), dim3(256), 0, stream>>>(
      x, W1p, W1n, b1p, b1n, lc1w, lc1b, lc2b, betaw, ws);

  vae_kernel<<<dim3(BB), dim3(128), 0, stream>>>(
      betaw, enc1w, enc1b, enc2w, enc2b, muw, mub, lvw, lvb,
      dec1w, dec1b, dec2w, dec2b, dec3w, dec3b, eps,
      mu_out, lv_out, reconT);

  main_kernel<<<dim3(1024), dim3(256), 0, stream>>>(
      lc2w, betab, (const char*)ws, out);
}